// Round 6
// baseline (1116.057 us; speedup 1.0000x reference)
//
#include <hip/hip_runtime.h>
#include <hip/hip_bf16.h>

#define DIM 64
#define SCAN_CHUNK 2048

typedef __bf16 bf16v8 __attribute__((ext_vector_type(8)));
typedef float f32v4 __attribute__((ext_vector_type(4)));

static inline int idiv(int a, int b) { return (a + b - 1) / b; }

__device__ inline unsigned short f2b(float f) {
    __hip_bfloat16 h = __float2bfloat16(f);
    return *reinterpret_cast<unsigned short*>(&h);
}

// ---------------- degrees + slot reservation ----------------
__global__ void k_degrees(const int* __restrict__ row, const int* __restrict__ col,
                          int* __restrict__ dr, int* __restrict__ dc,
                          int* __restrict__ slot_r, int* __restrict__ slot_c, int E) {
    int e = blockIdx.x * blockDim.x + threadIdx.x;
    if (e < E) {
        slot_r[e] = atomicAdd(&dr[row[e]], 1);
        slot_c[e] = atomicAdd(&dc[col[e]], 1);
    }
}

// ---------------- scan phase A: per-block partial sums ----------------
__global__ __launch_bounds__(256) void k_scan_blk(const int* __restrict__ deg_r,
                                                  const int* __restrict__ deg_c,
                                                  int* __restrict__ part, int n, int G) {
    int b = blockIdx.x;
    const int* deg = (b < G) ? deg_r : deg_c;
    int lb = (b < G) ? b : b - G;
    int base = lb * SCAN_CHUNK;
    int t = threadIdx.x;
    int s = 0;
    for (int i = t; i < SCAN_CHUNK; i += 256) {
        int g = base + i;
        if (g < n) s += deg[g];
    }
    __shared__ int red[256];
    red[t] = s;
    __syncthreads();
    for (int off = 128; off > 0; off >>= 1) {
        if (t < off) red[t] += red[t + off];
        __syncthreads();
    }
    if (t == 0) part[b] = red[0];
}

// ---------------- scan phase B: top scan (+ bias prep in spare block) ----------
__global__ __launch_bounds__(1024) void k_scan_top(int* __restrict__ part, int G,
        const float* __restrict__ bs_sd, const float* __restrict__ b0_sd,
        const float* __restrict__ bs_ds, const float* __restrict__ b0_ds,
        float* __restrict__ cb) {
    int t = threadIdx.x;
    if (blockIdx.x == 2) {
        if (t < 64) {
            float ssd = bs_sd[t] + b0_sd[t];
            float sds = bs_ds[t] + b0_ds[t];
            float sc = 1.f;
            for (int i = 1; i < 4; i++) {
                sc *= 0.5f;
                ssd += bs_sd[i * 64 + t] * sc;
                sds += bs_ds[i * 64 + t] * sc;
            }
            cb[t] = 0.5f * ssd + 0.5f * sds;  // ALPHA = 0.5
        }
        return;
    }
    int* p = part + ((blockIdx.x == 0) ? 0 : G);
    __shared__ int sums[1024];
    sums[t] = (t < G) ? p[t] : 0;
    __syncthreads();
    for (int off = 1; off < 1024; off <<= 1) {
        int v = (t >= off) ? sums[t - off] : 0;
        __syncthreads();
        sums[t] += v;
        __syncthreads();
    }
    if (t < G) p[t] = (t == 0) ? 0 : sums[t - 1];
}

// ---------------- scan phase C: finish — write ptr + inv ----------------
__global__ __launch_bounds__(256) void k_scan_fin(const int* __restrict__ deg_r,
                                                  const int* __restrict__ deg_c,
                                                  const int* __restrict__ part,
                                                  int* __restrict__ rptr, int* __restrict__ cptr,
                                                  float* __restrict__ inv_r, float* __restrict__ inv_c,
                                                  int n, int G) {
    int b = blockIdx.x;
    bool isr = (b < G);
    const int* deg = isr ? deg_r : deg_c;
    int* ptr = isr ? rptr : cptr;
    float* inv = isr ? inv_r : inv_c;
    int lb = isr ? b : b - G;
    int off = part[b];
    int base = lb * SCAN_CHUNK;
    int t = threadIdx.x;
    int start = base + t * 8;
    int v[8];
    int s = 0;
#pragma unroll
    for (int k = 0; k < 8; k++) {
        int g = start + k;
        int d = (g < n) ? deg[g] : 0;
        v[k] = d;
        s += d;
    }
    __shared__ int sums[256];
    sums[t] = s;
    __syncthreads();
    for (int o = 1; o < 256; o <<= 1) {
        int x = (t >= o) ? sums[t - o] : 0;
        __syncthreads();
        sums[t] += x;
        __syncthreads();
    }
    int run = off + ((t == 0) ? 0 : sums[t - 1]);
#pragma unroll
    for (int k = 0; k < 8; k++) {
        int g = start + k;
        if (g < n) {
            ptr[g] = run;
            inv[g] = (v[k] > 0) ? rsqrtf((float)v[k]) : 0.f;
            run += v[k];
        }
    }
    if (t == 255 && lb == G - 1) ptr[n] = run;  // grand total
}

// ---------------- CSR/CSC fill (atomic-free, packed idx+weight) ----------------
__global__ void k_fill(const int* __restrict__ row, const int* __restrict__ col,
                       const int* __restrict__ rptr, const int* __restrict__ cptr,
                       const int* __restrict__ slot_r, const int* __restrict__ slot_c,
                       const float* __restrict__ inv_r, const float* __restrict__ inv_c,
                       int2* __restrict__ adj, int2* __restrict__ adjT, int E) {
    int e = blockIdx.x * blockDim.x + threadIdx.x;
    if (e < E) {
        int r = row[e], c = col[e];
        adj[rptr[r] + slot_r[e]] = make_int2(c, __float_as_int(inv_c[c]));
        adjT[cptr[c] + slot_c[e]] = make_int2(r, __float_as_int(inv_r[r]));
    }
}

// ---------------- x -> bf16 cast ----------------
__global__ void k_xcast(const float* __restrict__ x, unsigned short* __restrict__ xb, int total) {
    int i = (blockIdx.x * blockDim.x + threadIdx.x) * 4;
    if (i < total) {
        float4 v = *reinterpret_cast<const float4*>(x + i);
        ushort4 o;
        o.x = f2b(v.x); o.y = f2b(v.y); o.z = f2b(v.z); o.w = f2b(v.w);
        *reinterpret_cast<ushort4*>(xb + i) = o;
    }
}

// ---------------- weight prep: bf16, scale prefolded, MFMA-frag-swizzled -------
// Mat order: 0:W0c(=0.5*(W0_sd+W0_ds)), then for hop i: (Wsd_i, Wds_i) at mats
// 2i+1, 2i+2 with scale 0.5*2^-i.  Swizzle: Wsw[((m*4+ot)*2+kh)*512 + lane*8 + j]
// = W_m[(ot*16+l16)*64 + kh*32 + q*8 + j]  (lane = q*16+l16) — so a wave's
// B-fragment is a lane-contiguous 16B ds_read_b128.
__global__ void k_wprep(const float* __restrict__ Ws_sd, const float* __restrict__ Ws_ds,
                        const float* __restrict__ W0_sd, const float* __restrict__ W0_ds,
                        unsigned short* __restrict__ Wsw) {
    int i = blockIdx.x * blockDim.x + threadIdx.x;  // 9*4096 total
    if (i >= 9 * 4096) return;
    int m = i >> 12, r = i & 4095;
    int frag = r >> 9, lane = (r >> 3) & 63, j = r & 7;
    int ot = frag >> 1, kh = frag & 1, q = lane >> 4, l16 = lane & 15;
    int src = (ot * 16 + l16) * 64 + kh * 32 + q * 8 + j;
    float v;
    if (m == 0) {
        v = 0.5f * (W0_sd[src] + W0_ds[src]);
    } else {
        int hop = (m - 1) >> 1;
        float sc = 0.5f / (float)(1 << hop);
        v = ((m & 1) ? Ws_sd[hop * 4096 + src] : Ws_ds[hop * 4096 + src]) * sc;
    }
    Wsw[i] = f2b(v);
}

// ---------------- SpMM (bf16 h, bf16 out, fp32 accum) ----------------
__global__ __launch_bounds__(256) void k_spmm(const unsigned short* __restrict__ h,
                                              unsigned short* __restrict__ out,
                                              const int* __restrict__ ptr,
                                              const int2* __restrict__ adj,
                                              const float* __restrict__ inv_self, int n) {
    int gw = (blockIdx.x * blockDim.x + threadIdx.x) >> 6;
    int lane = threadIdx.x & 63;
    if (gw >= n) return;
    int beg = ptr[gw], end = ptr[gw + 1];
    float acc = 0.f;
#pragma unroll 16
    for (int j = beg; j < end; j++) {
        int2 e = adj[j];
        __hip_bfloat16 hv;
        *reinterpret_cast<unsigned short*>(&hv) = h[e.x * DIM + lane];
        acc = fmaf(__int_as_float(e.y), __bfloat162float(hv), acc);
    }
    out[gw * DIM + lane] = f2b(inv_self[gw] * acc);
}

// ---------------- multi-matrix MFMA GEMM ----------------
// out (=|+=) [bias +] sum_m W_m h_m   for NM matrices; scales prefolded in W.
// Weights staged in LDS (frag-swizzled). One wave per 16-row tile, 4 ot tiles.
template <int NM, bool INIT>
__global__ __launch_bounds__(256) void k_mg(
        const unsigned short* __restrict__ h0, const unsigned short* __restrict__ h1,
        const unsigned short* __restrict__ h2, const unsigned short* __restrict__ h3,
        const unsigned short* __restrict__ h4,
        const unsigned short* __restrict__ Wsw,  // NM*4096 ushorts, frag-swizzled
        const float* __restrict__ cb, float* __restrict__ out, int n) {
    __shared__ int4 wlds4[NM * 512];  // NM*4096 ushorts, 16B units
    {
        const int4* src = reinterpret_cast<const int4*>(Wsw);
        for (int i = threadIdx.x; i < NM * 512; i += 256) wlds4[i] = src[i];
    }
    __syncthreads();
    const unsigned short* wlds = reinterpret_cast<const unsigned short*>(wlds4);

    const unsigned short* hs[5] = {h0, h1, h2, h3, h4};
    int lane = threadIdx.x & 63;
    int quad = lane >> 4;
    int l16 = lane & 15;
    int nmax = n - 1;
    float bias[4];
    if (INIT) {
#pragma unroll
        for (int ot = 0; ot < 4; ot++) bias[ot] = cb[ot * 16 + l16];
    }
    int tiles_all = (n + 15) >> 4;
    int wave = (blockIdx.x * blockDim.x + threadIdx.x) >> 6;
    int nw = (gridDim.x * blockDim.x) >> 6;
    for (int t = wave; t < tiles_all; t += nw) {
        int row0 = t << 4;
        int arow = min(row0 + l16, nmax);
        bf16v8 a[NM][2];
#pragma unroll
        for (int m = 0; m < NM; m++) {
            const bf16v8* p = reinterpret_cast<const bf16v8*>(hs[m] + (size_t)arow * 64 + quad * 8);
            a[m][0] = p[0];
            a[m][1] = p[4];
        }
        f32v4 acc[4];
        if (INIT) {
#pragma unroll
            for (int ot = 0; ot < 4; ot++) {
                float b = bias[ot];
                acc[ot] = f32v4{b, b, b, b};
            }
        } else {
#pragma unroll
            for (int ot = 0; ot < 4; ot++)
#pragma unroll
                for (int r = 0; r < 4; r++)
                    acc[ot][r] = out[(size_t)min(row0 + quad * 4 + r, nmax) * 64 + ot * 16 + l16];
        }
#pragma unroll
        for (int ot = 0; ot < 4; ot++) {
#pragma unroll
            for (int m = 0; m < NM; m++) {
#pragma unroll
                for (int kh = 0; kh < 2; kh++) {
                    bf16v8 w = *reinterpret_cast<const bf16v8*>(
                        wlds + ((size_t)((m * 4 + ot) * 2 + kh) * 512 + lane * 8));
                    acc[ot] = __builtin_amdgcn_mfma_f32_16x16x32_bf16(a[m][kh], w, acc[ot], 0, 0, 0);
                }
            }
        }
#pragma unroll
        for (int ot = 0; ot < 4; ot++)
#pragma unroll
            for (int r = 0; r < 4; r++) {
                int rr = row0 + quad * 4 + r;
                if (rr < n) out[(size_t)rr * 64 + ot * 16 + l16] = acc[ot][r];
            }
    }
}

extern "C" void kernel_launch(void* const* d_in, const int* in_sizes, int n_in,
                              void* d_out, int out_size, void* d_ws, size_t ws_size,
                              hipStream_t stream) {
    const float* x     = (const float*)d_in[0];
    const int*   ei    = (const int*)d_in[1];
    const float* Ws_sd = (const float*)d_in[2];
    const float* bs_sd = (const float*)d_in[3];
    const float* Ws_ds = (const float*)d_in[4];
    const float* bs_ds = (const float*)d_in[5];
    const float* W0_sd = (const float*)d_in[6];
    const float* b0_sd = (const float*)d_in[7];
    const float* W0_ds = (const float*)d_in[8];
    const float* b0_ds = (const float*)d_in[9];

    int N = in_sizes[0] / DIM;
    int E = in_sizes[1] / 2;
    const int* row = ei;
    const int* col = ei + E;
    float* out = (float*)d_out;

    int G = idiv(N, SCAN_CHUNK);  // blocks per scan array

    // workspace carve-up (64B-aligned chunks; sizes in bytes)
    char* wsp = (char*)d_ws;
    auto alloc = [&](size_t bytes) -> void* {
        void* p = (void*)wsp;
        wsp += ((bytes + 63) / 64) * 64;
        return p;
    };
    size_t bufBytes = ((((size_t)N * DIM * 2) + 63) / 64) * 64;

    int* degs   = (int*)alloc((size_t)2 * N * 4);
    int* deg_r  = degs;
    int* deg_c  = degs + N;
    int* rptr   = (int*)alloc(((size_t)N + 1) * 4);
    int* cptr   = (int*)alloc(((size_t)N + 1) * 4);
    int2* adj   = (int2*)alloc((size_t)E * 8);
    int2* adjT  = (int2*)alloc((size_t)E * 8);
    unsigned short* xb = (unsigned short*)alloc((size_t)N * DIM * 2);
    float* invs = (float*)alloc((size_t)2 * N * 4);
    float* inv_r = invs;
    float* inv_c = invs + N;
    float* cb   = (float*)alloc(64 * 4);
    unsigned short* Wsw = (unsigned short*)alloc((size_t)9 * 4096 * 2);
    int* part   = (int*)alloc((size_t)2 * G * 4);

    size_t fixed_used = (size_t)(wsp - (char*)d_ws);
    bool mega = (fixed_used + 4 * bufBytes) <= ws_size;  // deterministic per session

    unsigned short* bufA = (unsigned short*)alloc((size_t)N * DIM * 2);
    unsigned short* bufB = (unsigned short*)alloc((size_t)N * DIM * 2);
    unsigned short* bufC = mega ? (unsigned short*)alloc((size_t)N * DIM * 2) : nullptr;
    unsigned short* bufD = mega ? (unsigned short*)alloc((size_t)N * DIM * 2) : nullptr;

    // slot arrays alias bufA/bufB (first written by SpMM, after k_fill)
    int* slot_r = (int*)bufA;
    int* slot_c = (int*)bufB;

    hipMemsetAsync(degs, 0, (size_t)2 * N * sizeof(int), stream);

    k_degrees<<<idiv(E, 256), 256, 0, stream>>>(row, col, deg_r, deg_c, slot_r, slot_c, E);
    k_scan_blk<<<2 * G, 256, 0, stream>>>(deg_r, deg_c, part, N, G);
    k_scan_top<<<3, 1024, 0, stream>>>(part, G, bs_sd, b0_sd, bs_ds, b0_ds, cb);
    k_scan_fin<<<2 * G, 256, 0, stream>>>(deg_r, deg_c, part, rptr, cptr, inv_r, inv_c, N, G);
    k_fill<<<idiv(E, 256), 256, 0, stream>>>(row, col, rptr, cptr, slot_r, slot_c,
                                             inv_r, inv_c, adj, adjT, E);
    k_xcast<<<idiv(N * DIM / 4, 256), 256, 0, stream>>>(x, xb, N * DIM);
    k_wprep<<<144, 256, 0, stream>>>(Ws_sd, Ws_ds, W0_sd, W0_ds, Wsw);

    int spmmGrid = idiv(N * 64, 256);  // one wave per row
    int mgGrid = 1568;                 // 6272 wave-tiles >= ceil(N/16)

    if (mega) {
        // y0=A x->A ; yt0=A^T x->B ; y1=A y0->C ; yt1=A^T y1->D
        k_spmm<<<spmmGrid, 256, 0, stream>>>(xb, bufA, rptr, adj, inv_r, N);
        k_spmm<<<spmmGrid, 256, 0, stream>>>(xb, bufB, cptr, adjT, inv_c, N);
        k_spmm<<<spmmGrid, 256, 0, stream>>>(bufA, bufC, rptr, adj, inv_r, N);
        k_spmm<<<spmmGrid, 256, 0, stream>>>(bufC, bufD, cptr, adjT, inv_c, N);
        // out = cb + W0c x + Wsd0 y0 + Wds0 yt0 + Wsd1 y1 + Wds1 yt1   (mats 0..4)
        k_mg<5, true><<<mgGrid, 256, 0, stream>>>(xb, bufA, bufB, bufC, bufD, Wsw, cb, out, N);
        // y2=A y1->A ; yt2=A^T y2->B ; y3=A y2->C' (old D free? keep simple: ->D later)
        k_spmm<<<spmmGrid, 256, 0, stream>>>(bufC, bufA, rptr, adj, inv_r, N);
        k_spmm<<<spmmGrid, 256, 0, stream>>>(bufA, bufB, cptr, adjT, inv_c, N);
        k_spmm<<<spmmGrid, 256, 0, stream>>>(bufA, bufC, rptr, adj, inv_r, N);
        k_spmm<<<spmmGrid, 256, 0, stream>>>(bufC, bufD, cptr, adjT, inv_c, N);
        // out += Wsd2 y2 + Wds2 yt2 + Wsd3 y3 + Wds3 yt3   (mats 5..8)
        k_mg<4, false><<<mgGrid, 256, 0, stream>>>(bufA, bufB, bufC, bufD, nullptr,
                                                   Wsw + (size_t)5 * 4096, cb, out, N);
    } else {
        // fallback: round-5 structure with 2 rotating buffers
        k_spmm<<<spmmGrid, 256, 0, stream>>>(xb, bufA, rptr, adj, inv_r, N);
        k_spmm<<<spmmGrid, 256, 0, stream>>>(xb, bufB, cptr, adjT, inv_c, N);
        k_mg<3, true><<<mgGrid, 256, 0, stream>>>(xb, bufA, bufB, nullptr, nullptr, Wsw, cb, out, N);
        unsigned short* ycur = bufA;
        unsigned short* yfree = bufB;
        for (int i = 1; i < 4; i++) {
            k_spmm<<<spmmGrid, 256, 0, stream>>>(ycur, yfree, rptr, adj, inv_r, N);
            k_spmm<<<spmmGrid, 256, 0, stream>>>(yfree, ycur, cptr, adjT, inv_c, N);
            k_mg<2, false><<<mgGrid, 256, 0, stream>>>(yfree, ycur, nullptr, nullptr, nullptr,
                                                       Wsw + (size_t)(2 * i + 1) * 4096, cb, out, N);
            unsigned short* t = ycur; ycur = yfree; yfree = t;
        }
    }
}

// Round 7
// 1105.125 us; speedup vs baseline: 1.0099x; 1.0099x over previous
//
#include <hip/hip_runtime.h>
#include <hip/hip_bf16.h>

#define DIM 64
#define SCAN_CHUNK 2048

typedef __bf16 bf16v8 __attribute__((ext_vector_type(8)));
typedef float f32v4 __attribute__((ext_vector_type(4)));

static inline int idiv(int a, int b) { return (a + b - 1) / b; }

__device__ inline unsigned short f2b(float f) {
    __hip_bfloat16 h = __float2bfloat16(f);
    return *reinterpret_cast<unsigned short*>(&h);
}

// ---------------- degrees + slot reservation ----------------
__global__ void k_degrees(const int* __restrict__ row, const int* __restrict__ col,
                          int* __restrict__ dr, int* __restrict__ dc,
                          int* __restrict__ slot_r, int* __restrict__ slot_c, int E) {
    int e = blockIdx.x * blockDim.x + threadIdx.x;
    if (e < E) {
        slot_r[e] = atomicAdd(&dr[row[e]], 1);
        slot_c[e] = atomicAdd(&dc[col[e]], 1);
    }
}

// ---------------- scan phase A: per-block partial sums ----------------
__global__ __launch_bounds__(256) void k_scan_blk(const int* __restrict__ deg_r,
                                                  const int* __restrict__ deg_c,
                                                  int* __restrict__ part, int n, int G) {
    int b = blockIdx.x;
    const int* deg = (b < G) ? deg_r : deg_c;
    int lb = (b < G) ? b : b - G;
    int base = lb * SCAN_CHUNK;
    int t = threadIdx.x;
    int s = 0;
    for (int i = t; i < SCAN_CHUNK; i += 256) {
        int g = base + i;
        if (g < n) s += deg[g];
    }
    __shared__ int red[256];
    red[t] = s;
    __syncthreads();
    for (int off = 128; off > 0; off >>= 1) {
        if (t < off) red[t] += red[t + off];
        __syncthreads();
    }
    if (t == 0) part[b] = red[0];
}

// ---------------- scan phase B: top scan (+ bias prep in spare block) ----------
__global__ __launch_bounds__(1024) void k_scan_top(int* __restrict__ part, int G,
        const float* __restrict__ bs_sd, const float* __restrict__ b0_sd,
        const float* __restrict__ bs_ds, const float* __restrict__ b0_ds,
        float* __restrict__ cb) {
    int t = threadIdx.x;
    if (blockIdx.x == 2) {
        if (t < 64) {
            float ssd = bs_sd[t] + b0_sd[t];
            float sds = bs_ds[t] + b0_ds[t];
            float sc = 1.f;
            for (int i = 1; i < 4; i++) {
                sc *= 0.5f;
                ssd += bs_sd[i * 64 + t] * sc;
                sds += bs_ds[i * 64 + t] * sc;
            }
            cb[t] = 0.5f * ssd + 0.5f * sds;  // ALPHA = 0.5
        }
        return;
    }
    int* p = part + ((blockIdx.x == 0) ? 0 : G);
    __shared__ int sums[1024];
    sums[t] = (t < G) ? p[t] : 0;
    __syncthreads();
    for (int off = 1; off < 1024; off <<= 1) {
        int v = (t >= off) ? sums[t - off] : 0;
        __syncthreads();
        sums[t] += v;
        __syncthreads();
    }
    if (t < G) p[t] = (t == 0) ? 0 : sums[t - 1];
}

// ---------------- scan phase C: finish — write ptr + inv ----------------
__global__ __launch_bounds__(256) void k_scan_fin(const int* __restrict__ deg_r,
                                                  const int* __restrict__ deg_c,
                                                  const int* __restrict__ part,
                                                  int* __restrict__ rptr, int* __restrict__ cptr,
                                                  float* __restrict__ inv_r, float* __restrict__ inv_c,
                                                  int n, int G) {
    int b = blockIdx.x;
    bool isr = (b < G);
    const int* deg = isr ? deg_r : deg_c;
    int* ptr = isr ? rptr : cptr;
    float* inv = isr ? inv_r : inv_c;
    int lb = isr ? b : b - G;
    int off = part[b];
    int base = lb * SCAN_CHUNK;
    int t = threadIdx.x;
    int start = base + t * 8;
    int v[8];
    int s = 0;
#pragma unroll
    for (int k = 0; k < 8; k++) {
        int g = start + k;
        int d = (g < n) ? deg[g] : 0;
        v[k] = d;
        s += d;
    }
    __shared__ int sums[256];
    sums[t] = s;
    __syncthreads();
    for (int o = 1; o < 256; o <<= 1) {
        int x = (t >= o) ? sums[t - o] : 0;
        __syncthreads();
        sums[t] += x;
        __syncthreads();
    }
    int run = off + ((t == 0) ? 0 : sums[t - 1]);
#pragma unroll
    for (int k = 0; k < 8; k++) {
        int g = start + k;
        if (g < n) {
            ptr[g] = run;
            inv[g] = (v[k] > 0) ? rsqrtf((float)v[k]) : 0.f;
            run += v[k];
        }
    }
    if (t == 255 && lb == G - 1) ptr[n] = run;  // grand total
}

// ---------------- CSR/CSC fill (atomic-free, packed idx+weight) ----------------
__global__ void k_fill(const int* __restrict__ row, const int* __restrict__ col,
                       const int* __restrict__ rptr, const int* __restrict__ cptr,
                       const int* __restrict__ slot_r, const int* __restrict__ slot_c,
                       const float* __restrict__ inv_r, const float* __restrict__ inv_c,
                       int2* __restrict__ adj, int2* __restrict__ adjT, int E) {
    int e = blockIdx.x * blockDim.x + threadIdx.x;
    if (e < E) {
        int r = row[e], c = col[e];
        adj[rptr[r] + slot_r[e]] = make_int2(c, __float_as_int(inv_c[c]));
        adjT[cptr[c] + slot_c[e]] = make_int2(r, __float_as_int(inv_r[r]));
    }
}

// ---------------- x -> bf16 cast ----------------
__global__ void k_xcast(const float* __restrict__ x, unsigned short* __restrict__ xb, int total) {
    int i = (blockIdx.x * blockDim.x + threadIdx.x) * 4;
    if (i < total) {
        float4 v = *reinterpret_cast<const float4*>(x + i);
        ushort4 o;
        o.x = f2b(v.x); o.y = f2b(v.y); o.z = f2b(v.z); o.w = f2b(v.w);
        *reinterpret_cast<ushort4*>(xb + i) = o;
    }
}

// ---------------- weight prep: bf16 cast, scale prefolded ----------------
// Mat order: 0:W0c(=0.5*(W0_sd+W0_ds)); m=2i+1:0.5*2^-i*Ws_sd[i]; m=2i+2:0.5*2^-i*Ws_ds[i]
__global__ void k_wprep(const float* __restrict__ Ws_sd, const float* __restrict__ Ws_ds,
                        const float* __restrict__ W0_sd, const float* __restrict__ W0_ds,
                        unsigned short* __restrict__ Wall) {
    int i = blockIdx.x * blockDim.x + threadIdx.x;  // 9*4096 total
    if (i >= 9 * 4096) return;
    int m = i >> 12, src = i & 4095;
    float v;
    if (m == 0) {
        v = 0.5f * (W0_sd[src] + W0_ds[src]);
    } else {
        int hop = (m - 1) >> 1;
        float sc = 0.5f / (float)(1 << hop);
        bool sd = ((m - 1) & 1) == 0;  // m=1,3,5,7 -> Ws_sd
        v = (sd ? Ws_sd : Ws_ds)[hop * 4096 + src] * sc;
    }
    Wall[i] = f2b(v);
}

// ---------------- SpMM (bf16 h, bf16 out, fp32 accum) ----------------
__global__ __launch_bounds__(256) void k_spmm(const unsigned short* __restrict__ h,
                                              unsigned short* __restrict__ out,
                                              const int* __restrict__ ptr,
                                              const int2* __restrict__ adj,
                                              const float* __restrict__ inv_self, int n) {
    int gw = (blockIdx.x * blockDim.x + threadIdx.x) >> 6;
    int lane = threadIdx.x & 63;
    if (gw >= n) return;
    int beg = ptr[gw], end = ptr[gw + 1];
    float acc = 0.f;
#pragma unroll 16
    for (int j = beg; j < end; j++) {
        int2 e = adj[j];
        __hip_bfloat16 hv;
        *reinterpret_cast<unsigned short*>(&hv) = h[e.x * DIM + lane];
        acc = fmaf(__int_as_float(e.y), __bfloat162float(hv), acc);
    }
    out[gw * DIM + lane] = f2b(inv_self[gw] * acc);
}

// ---------------- multi-matrix MFMA GEMM, VGPR-resident weights ----------------
// out (=|+=) [bias +] sum_m W_m h_m ; scales prefolded into W. No LDS.
// One wave per 16-row tile; weights loaded once per wave, amortized via
// grid-stride loop (grid sized so each wave handles several tiles).
template <int NM, bool INIT>
__global__ __launch_bounds__(256, 2) void k_mg(
        const unsigned short* __restrict__ h0, const unsigned short* __restrict__ h1,
        const unsigned short* __restrict__ h2, const unsigned short* __restrict__ h3,
        const unsigned short* __restrict__ h4,
        const unsigned short* __restrict__ W,  // NM consecutive 64x64 bf16 mats
        const float* __restrict__ cb, float* __restrict__ out, int n) {
    const unsigned short* hs[5] = {h0, h1, h2, h3, h4};
    int lane = threadIdx.x & 63;
    int quad = lane >> 4;
    int l16 = lane & 15;
    int nmax = n - 1;

    bf16v8 w[NM][4][2];
#pragma unroll
    for (int m = 0; m < NM; m++)
#pragma unroll
        for (int ot = 0; ot < 4; ot++)
#pragma unroll
            for (int kh = 0; kh < 2; kh++)
                w[m][ot][kh] = *reinterpret_cast<const bf16v8*>(
                    W + (size_t)m * 4096 + (ot * 16 + l16) * 64 + kh * 32 + quad * 8);

    float bias[4];
    if (INIT) {
#pragma unroll
        for (int ot = 0; ot < 4; ot++) bias[ot] = cb[ot * 16 + l16];
    }
    int tiles_all = (n + 15) >> 4;
    int wave = (blockIdx.x * blockDim.x + threadIdx.x) >> 6;
    int nw = (gridDim.x * blockDim.x) >> 6;
    for (int t = wave; t < tiles_all; t += nw) {
        int row0 = t << 4;
        int arow = min(row0 + l16, nmax);
        bf16v8 a[NM][2];
#pragma unroll
        for (int m = 0; m < NM; m++) {
            const bf16v8* p = reinterpret_cast<const bf16v8*>(hs[m] + (size_t)arow * 64 + quad * 8);
            a[m][0] = p[0];
            a[m][1] = p[4];
        }
        f32v4 acc[4];
        if (INIT) {
#pragma unroll
            for (int ot = 0; ot < 4; ot++) {
                float b = bias[ot];
                acc[ot] = f32v4{b, b, b, b};
            }
        } else {
#pragma unroll
            for (int ot = 0; ot < 4; ot++)
#pragma unroll
                for (int r = 0; r < 4; r++)
                    acc[ot][r] = out[(size_t)min(row0 + quad * 4 + r, nmax) * 64 + ot * 16 + l16];
        }
#pragma unroll
        for (int ot = 0; ot < 4; ot++)
#pragma unroll
            for (int m = 0; m < NM; m++) {
                acc[ot] = __builtin_amdgcn_mfma_f32_16x16x32_bf16(a[m][0], w[m][ot][0], acc[ot], 0, 0, 0);
                acc[ot] = __builtin_amdgcn_mfma_f32_16x16x32_bf16(a[m][1], w[m][ot][1], acc[ot], 0, 0, 0);
            }
#pragma unroll
        for (int ot = 0; ot < 4; ot++)
#pragma unroll
            for (int r = 0; r < 4; r++) {
                int rr = row0 + quad * 4 + r;
                if (rr < n) out[(size_t)rr * 64 + ot * 16 + l16] = acc[ot][r];
            }
    }
}

extern "C" void kernel_launch(void* const* d_in, const int* in_sizes, int n_in,
                              void* d_out, int out_size, void* d_ws, size_t ws_size,
                              hipStream_t stream) {
    const float* x     = (const float*)d_in[0];
    const int*   ei    = (const int*)d_in[1];
    const float* Ws_sd = (const float*)d_in[2];
    const float* bs_sd = (const float*)d_in[3];
    const float* Ws_ds = (const float*)d_in[4];
    const float* bs_ds = (const float*)d_in[5];
    const float* W0_sd = (const float*)d_in[6];
    const float* b0_sd = (const float*)d_in[7];
    const float* W0_ds = (const float*)d_in[8];
    const float* b0_ds = (const float*)d_in[9];

    int N = in_sizes[0] / DIM;
    int E = in_sizes[1] / 2;
    const int* row = ei;
    const int* col = ei + E;
    float* out = (float*)d_out;

    int G = idiv(N, SCAN_CHUNK);  // blocks per scan array

    // workspace carve-up (64B-aligned chunks; sizes in bytes)
    char* wsp = (char*)d_ws;
    auto alloc = [&](size_t bytes) -> void* {
        void* p = (void*)wsp;
        wsp += ((bytes + 63) / 64) * 64;
        return p;
    };
    size_t bufBytes = ((((size_t)N * DIM * 2) + 63) / 64) * 64;

    int* degs   = (int*)alloc((size_t)2 * N * 4);
    int* deg_r  = degs;
    int* deg_c  = degs + N;
    int* rptr   = (int*)alloc(((size_t)N + 1) * 4);
    int* cptr   = (int*)alloc(((size_t)N + 1) * 4);
    int2* adj   = (int2*)alloc((size_t)E * 8);
    int2* adjT  = (int2*)alloc((size_t)E * 8);
    unsigned short* xb = (unsigned short*)alloc((size_t)N * DIM * 2);
    float* invs = (float*)alloc((size_t)2 * N * 4);
    float* inv_r = invs;
    float* inv_c = invs + N;
    float* cb   = (float*)alloc(64 * 4);
    unsigned short* Wall = (unsigned short*)alloc((size_t)9 * 4096 * 2);
    int* part   = (int*)alloc((size_t)2 * G * 4);

    size_t fixed_used = (size_t)(wsp - (char*)d_ws);
    bool mega = (fixed_used + 4 * bufBytes) <= ws_size;  // deterministic per session

    unsigned short* bufA = (unsigned short*)alloc((size_t)N * DIM * 2);
    unsigned short* bufB = (unsigned short*)alloc((size_t)N * DIM * 2);
    unsigned short* bufC = mega ? (unsigned short*)alloc((size_t)N * DIM * 2) : nullptr;
    unsigned short* bufD = mega ? (unsigned short*)alloc((size_t)N * DIM * 2) : nullptr;

    // slot arrays alias bufA/bufB (first written by SpMM, after k_fill)
    int* slot_r = (int*)bufA;
    int* slot_c = (int*)bufB;

    hipMemsetAsync(degs, 0, (size_t)2 * N * sizeof(int), stream);

    k_degrees<<<idiv(E, 256), 256, 0, stream>>>(row, col, deg_r, deg_c, slot_r, slot_c, E);
    k_scan_blk<<<2 * G, 256, 0, stream>>>(deg_r, deg_c, part, N, G);
    k_scan_top<<<3, 1024, 0, stream>>>(part, G, bs_sd, b0_sd, bs_ds, b0_ds, cb);
    k_scan_fin<<<2 * G, 256, 0, stream>>>(deg_r, deg_c, part, rptr, cptr, inv_r, inv_c, N, G);
    k_fill<<<idiv(E, 256), 256, 0, stream>>>(row, col, rptr, cptr, slot_r, slot_c,
                                             inv_r, inv_c, adj, adjT, E);
    k_xcast<<<idiv(N * DIM / 4, 256), 256, 0, stream>>>(x, xb, N * DIM);
    k_wprep<<<144, 256, 0, stream>>>(Ws_sd, Ws_ds, W0_sd, W0_ds, Wall);

    int spmmGrid = idiv(N * 64, 256);  // one wave per row
    int mgGrid = 384;                  // 1536 waves, ~4 tiles/wave: amortizes VGPR weight load

    if (mega) {
        // y0=A x->A ; yt0=A^T x->B ; y1=A y0->C ; yt1=A^T y1->D
        k_spmm<<<spmmGrid, 256, 0, stream>>>(xb, bufA, rptr, adj, inv_r, N);
        k_spmm<<<spmmGrid, 256, 0, stream>>>(xb, bufB, cptr, adjT, inv_c, N);
        k_spmm<<<spmmGrid, 256, 0, stream>>>(bufA, bufC, rptr, adj, inv_r, N);
        k_spmm<<<spmmGrid, 256, 0, stream>>>(bufC, bufD, cptr, adjT, inv_c, N);
        // out = cb + W0c x + Wsd0 y0 + Wds0 yt0 + Wsd1 y1 + Wds1 yt1   (mats 0..4)
        k_mg<5, true><<<mgGrid, 256, 0, stream>>>(xb, bufA, bufB, bufC, bufD, Wall, cb, out, N);
        // y2=A y1->A ; yt2=A^T y2->B ; y3=A y2->C ; yt3=A^T y3->D
        k_spmm<<<spmmGrid, 256, 0, stream>>>(bufC, bufA, rptr, adj, inv_r, N);
        k_spmm<<<spmmGrid, 256, 0, stream>>>(bufA, bufB, cptr, adjT, inv_c, N);
        k_spmm<<<spmmGrid, 256, 0, stream>>>(bufA, bufC, rptr, adj, inv_r, N);
        k_spmm<<<spmmGrid, 256, 0, stream>>>(bufC, bufD, cptr, adjT, inv_c, N);
        // out += Wsd2 y2 + Wds2 yt2 + Wsd3 y3 + Wds3 yt3   (mats 5..8)
        k_mg<4, false><<<mgGrid, 256, 0, stream>>>(bufA, bufB, bufC, bufD, nullptr,
                                                   Wall + (size_t)5 * 4096, cb, out, N);
    } else {
        // fallback: round-5 structure with 2 rotating buffers
        k_spmm<<<spmmGrid, 256, 0, stream>>>(xb, bufA, rptr, adj, inv_r, N);
        k_spmm<<<spmmGrid, 256, 0, stream>>>(xb, bufB, cptr, adjT, inv_c, N);
        k_mg<3, true><<<mgGrid, 256, 0, stream>>>(xb, bufA, bufB, nullptr, nullptr, Wall, cb, out, N);
        unsigned short* ycur = bufA;
        unsigned short* yfree = bufB;
        for (int i = 1; i < 4; i++) {
            k_spmm<<<spmmGrid, 256, 0, stream>>>(ycur, yfree, rptr, adj, inv_r, N);
            k_spmm<<<spmmGrid, 256, 0, stream>>>(yfree, ycur, cptr, adjT, inv_c, N);
            k_mg<2, false><<<mgGrid, 256, 0, stream>>>(yfree, ycur, nullptr, nullptr, nullptr,
                                                       Wall + (size_t)(2 * i + 1) * 4096, cb, out, N);
            unsigned short* t = ycur; ycur = yfree; yfree = t;
        }
    }
}

// Round 8
// 897.211 us; speedup vs baseline: 1.2439x; 1.2317x over previous
//
#include <hip/hip_runtime.h>
#include <hip/hip_bf16.h>

#define DIM 64
#define SCAN_CHUNK 2048

typedef __bf16 bf16v8 __attribute__((ext_vector_type(8)));
typedef float f32v4 __attribute__((ext_vector_type(4)));

static inline int idiv(int a, int b) { return (a + b - 1) / b; }

__device__ inline unsigned short f2b(float f) {
    __hip_bfloat16 h = __float2bfloat16(f);
    return *reinterpret_cast<unsigned short*>(&h);
}
__device__ inline float b2f(unsigned short u) {
    __hip_bfloat16 h;
    *reinterpret_cast<unsigned short*>(&h) = u;
    return __bfloat162float(h);
}

// ---------------- degrees + slot reservation (packed int2 slot store) ----------
__global__ void k_degrees(const int* __restrict__ row, const int* __restrict__ col,
                          int* __restrict__ dr, int* __restrict__ dc,
                          int2* __restrict__ slot, int E) {
    int e = blockIdx.x * blockDim.x + threadIdx.x;
    if (e < E) {
        int sr = atomicAdd(&dr[row[e]], 1);
        int sc = atomicAdd(&dc[col[e]], 1);
        slot[e] = make_int2(sr, sc);
    }
}

// ---------------- scan phase A: per-block partial sums ----------------
__global__ __launch_bounds__(256) void k_scan_blk(const int* __restrict__ deg_r,
                                                  const int* __restrict__ deg_c,
                                                  int* __restrict__ part, int n, int G) {
    int b = blockIdx.x;
    const int* deg = (b < G) ? deg_r : deg_c;
    int lb = (b < G) ? b : b - G;
    int base = lb * SCAN_CHUNK;
    int t = threadIdx.x;
    int s = 0;
    for (int i = t; i < SCAN_CHUNK; i += 256) {
        int g = base + i;
        if (g < n) s += deg[g];
    }
    __shared__ int red[256];
    red[t] = s;
    __syncthreads();
    for (int off = 128; off > 0; off >>= 1) {
        if (t < off) red[t] += red[t + off];
        __syncthreads();
    }
    if (t == 0) part[b] = red[0];
}

// ---------------- scan phase B: top scan (+ bias prep in spare block) ----------
__global__ __launch_bounds__(1024) void k_scan_top(int* __restrict__ part, int G,
        const float* __restrict__ bs_sd, const float* __restrict__ b0_sd,
        const float* __restrict__ bs_ds, const float* __restrict__ b0_ds,
        float* __restrict__ cb) {
    int t = threadIdx.x;
    if (blockIdx.x == 2) {
        if (t < 64) {
            float ssd = bs_sd[t] + b0_sd[t];
            float sds = bs_ds[t] + b0_ds[t];
            float sc = 1.f;
            for (int i = 1; i < 4; i++) {
                sc *= 0.5f;
                ssd += bs_sd[i * 64 + t] * sc;
                sds += bs_ds[i * 64 + t] * sc;
            }
            cb[t] = 0.5f * ssd + 0.5f * sds;  // ALPHA = 0.5
        }
        return;
    }
    int* p = part + ((blockIdx.x == 0) ? 0 : G);
    __shared__ int sums[1024];
    sums[t] = (t < G) ? p[t] : 0;
    __syncthreads();
    for (int off = 1; off < 1024; off <<= 1) {
        int v = (t >= off) ? sums[t - off] : 0;
        __syncthreads();
        sums[t] += v;
        __syncthreads();
    }
    if (t < G) p[t] = (t == 0) ? 0 : sums[t - 1];
}

// ---------------- scan phase C: finish — write ptr + inv ----------------
__global__ __launch_bounds__(256) void k_scan_fin(const int* __restrict__ deg_r,
                                                  const int* __restrict__ deg_c,
                                                  const int* __restrict__ part,
                                                  int* __restrict__ rptr, int* __restrict__ cptr,
                                                  float* __restrict__ inv_r, float* __restrict__ inv_c,
                                                  int n, int G) {
    int b = blockIdx.x;
    bool isr = (b < G);
    const int* deg = isr ? deg_r : deg_c;
    int* ptr = isr ? rptr : cptr;
    float* inv = isr ? inv_r : inv_c;
    int lb = isr ? b : b - G;
    int off = part[b];
    int base = lb * SCAN_CHUNK;
    int t = threadIdx.x;
    int start = base + t * 8;
    int v[8];
    int s = 0;
#pragma unroll
    for (int k = 0; k < 8; k++) {
        int g = start + k;
        int d = (g < n) ? deg[g] : 0;
        v[k] = d;
        s += d;
    }
    __shared__ int sums[256];
    sums[t] = s;
    __syncthreads();
    for (int o = 1; o < 256; o <<= 1) {
        int x = (t >= o) ? sums[t - o] : 0;
        __syncthreads();
        sums[t] += x;
        __syncthreads();
    }
    int run = off + ((t == 0) ? 0 : sums[t - 1]);
#pragma unroll
    for (int k = 0; k < 8; k++) {
        int g = start + k;
        if (g < n) {
            ptr[g] = run;
            inv[g] = (v[k] > 0) ? rsqrtf((float)v[k]) : 0.f;
            run += v[k];
        }
    }
    if (t == 255 && lb == G - 1) ptr[n] = run;  // grand total
}

// ---------------- CSR/CSC fill (atomic-free, packed idx+weight) ----------------
__global__ void k_fill(const int* __restrict__ row, const int* __restrict__ col,
                       const int* __restrict__ rptr, const int* __restrict__ cptr,
                       const int2* __restrict__ slot,
                       const float* __restrict__ inv_r, const float* __restrict__ inv_c,
                       int2* __restrict__ adj, int2* __restrict__ adjT, int E) {
    int e = blockIdx.x * blockDim.x + threadIdx.x;
    if (e < E) {
        int r = row[e], c = col[e];
        int2 s = slot[e];
        adj[rptr[r] + s.x] = make_int2(c, __float_as_int(inv_c[c]));
        adjT[cptr[c] + s.y] = make_int2(r, __float_as_int(inv_r[r]));
    }
}

// ---------------- x -> bf16 cast ----------------
__global__ void k_xcast(const float* __restrict__ x, unsigned short* __restrict__ xb, int total) {
    int i = (blockIdx.x * blockDim.x + threadIdx.x) * 4;
    if (i < total) {
        float4 v = *reinterpret_cast<const float4*>(x + i);
        ushort4 o;
        o.x = f2b(v.x); o.y = f2b(v.y); o.z = f2b(v.z); o.w = f2b(v.w);
        *reinterpret_cast<ushort4*>(xb + i) = o;
    }
}

// ---------------- weight prep: bf16 cast, scale prefolded ----------------
// Mat order: 0:W0c(=0.5*(W0_sd+W0_ds)); m=2i+1:0.5*2^-i*Ws_sd[i]; m=2i+2:0.5*2^-i*Ws_ds[i]
__global__ void k_wprep(const float* __restrict__ Ws_sd, const float* __restrict__ Ws_ds,
                        const float* __restrict__ W0_sd, const float* __restrict__ W0_ds,
                        unsigned short* __restrict__ Wall) {
    int i = blockIdx.x * blockDim.x + threadIdx.x;  // 9*4096 total
    if (i >= 9 * 4096) return;
    int m = i >> 12, src = i & 4095;
    float v;
    if (m == 0) {
        v = 0.5f * (W0_sd[src] + W0_ds[src]);
    } else {
        int hop = (m - 1) >> 1;
        float sc = 0.5f / (float)(1 << hop);
        bool sd = ((m - 1) & 1) == 0;  // m=1,3,5,7 -> Ws_sd
        v = (sd ? Ws_sd : Ws_ds)[hop * 4096 + src] * sc;
    }
    Wall[i] = f2b(v);
}

// ---------------- SpMM (bf16 h, bf16 out, fp32 accum) — round-5-proven body ----
// one wave per row, lane = feature; packed (c,w) edges. unroll 8 (mean degree is
// 16: unroll 16 starves the main loop and regressed ~60% — round 6/7 post-mortem).
__global__ __launch_bounds__(256) void k_spmm(const unsigned short* __restrict__ h,
                                              unsigned short* __restrict__ out,
                                              const int* __restrict__ ptr,
                                              const int2* __restrict__ adj,
                                              const float* __restrict__ inv_self, int n) {
    int gw = (blockIdx.x * blockDim.x + threadIdx.x) >> 6;
    int lane = threadIdx.x & 63;
    if (gw >= n) return;
    int beg = ptr[gw], end = ptr[gw + 1];
    float acc = 0.f;
#pragma unroll 8
    for (int j = beg; j < end; j++) {
        int2 e = adj[j];
        acc = fmaf(__int_as_float(e.y), b2f(h[e.x * DIM + lane]), acc);
    }
    out[gw * DIM + lane] = f2b(inv_self[gw] * acc);
}

// ---------------- multi-matrix MFMA GEMM, VGPR-resident weights ----------------
// out (=|+=) [bias +] sum_m W_m h_m ; scales prefolded into W. No LDS.
template <int NM, bool INIT>
__global__ __launch_bounds__(256, 2) void k_mg(
        const unsigned short* __restrict__ h0, const unsigned short* __restrict__ h1,
        const unsigned short* __restrict__ h2, const unsigned short* __restrict__ h3,
        const unsigned short* __restrict__ h4,
        const unsigned short* __restrict__ W,  // NM consecutive 64x64 bf16 mats
        const float* __restrict__ cb, float* __restrict__ out, int n) {
    const unsigned short* hs[5] = {h0, h1, h2, h3, h4};
    int lane = threadIdx.x & 63;
    int quad = lane >> 4;
    int l16 = lane & 15;
    int nmax = n - 1;

    bf16v8 w[NM][4][2];
#pragma unroll
    for (int m = 0; m < NM; m++)
#pragma unroll
        for (int ot = 0; ot < 4; ot++)
#pragma unroll
            for (int kh = 0; kh < 2; kh++)
                w[m][ot][kh] = *reinterpret_cast<const bf16v8*>(
                    W + (size_t)m * 4096 + (ot * 16 + l16) * 64 + kh * 32 + quad * 8);

    float bias[4];
    if (INIT) {
#pragma unroll
        for (int ot = 0; ot < 4; ot++) bias[ot] = cb[ot * 16 + l16];
    }
    int tiles_all = (n + 15) >> 4;
    int wave = (blockIdx.x * blockDim.x + threadIdx.x) >> 6;
    int nw = (gridDim.x * blockDim.x) >> 6;
    for (int t = wave; t < tiles_all; t += nw) {
        int row0 = t << 4;
        int arow = min(row0 + l16, nmax);
        bf16v8 a[NM][2];
#pragma unroll
        for (int m = 0; m < NM; m++) {
            const bf16v8* p = reinterpret_cast<const bf16v8*>(hs[m] + (size_t)arow * 64 + quad * 8);
            a[m][0] = p[0];
            a[m][1] = p[4];
        }
        f32v4 acc[4];
        if (INIT) {
#pragma unroll
            for (int ot = 0; ot < 4; ot++) {
                float b = bias[ot];
                acc[ot] = f32v4{b, b, b, b};
            }
        } else {
#pragma unroll
            for (int ot = 0; ot < 4; ot++)
#pragma unroll
                for (int r = 0; r < 4; r++)
                    acc[ot][r] = out[(size_t)min(row0 + quad * 4 + r, nmax) * 64 + ot * 16 + l16];
        }
#pragma unroll
        for (int ot = 0; ot < 4; ot++)
#pragma unroll
            for (int m = 0; m < NM; m++) {
                acc[ot] = __builtin_amdgcn_mfma_f32_16x16x32_bf16(a[m][0], w[m][ot][0], acc[ot], 0, 0, 0);
                acc[ot] = __builtin_amdgcn_mfma_f32_16x16x32_bf16(a[m][1], w[m][ot][1], acc[ot], 0, 0, 0);
            }
#pragma unroll
        for (int ot = 0; ot < 4; ot++)
#pragma unroll
            for (int r = 0; r < 4; r++) {
                int rr = row0 + quad * 4 + r;
                if (rr < n) out[(size_t)rr * 64 + ot * 16 + l16] = acc[ot][r];
            }
    }
}

extern "C" void kernel_launch(void* const* d_in, const int* in_sizes, int n_in,
                              void* d_out, int out_size, void* d_ws, size_t ws_size,
                              hipStream_t stream) {
    const float* x     = (const float*)d_in[0];
    const int*   ei    = (const int*)d_in[1];
    const float* Ws_sd = (const float*)d_in[2];
    const float* bs_sd = (const float*)d_in[3];
    const float* Ws_ds = (const float*)d_in[4];
    const float* bs_ds = (const float*)d_in[5];
    const float* W0_sd = (const float*)d_in[6];
    const float* b0_sd = (const float*)d_in[7];
    const float* W0_ds = (const float*)d_in[8];
    const float* b0_ds = (const float*)d_in[9];

    int N = in_sizes[0] / DIM;
    int E = in_sizes[1] / 2;
    const int* row = ei;
    const int* col = ei + E;
    float* out = (float*)d_out;

    int G = idiv(N, SCAN_CHUNK);  // blocks per scan array

    // workspace carve-up (64B-aligned chunks; sizes in bytes)
    char* wsp = (char*)d_ws;
    auto alloc = [&](size_t bytes) -> void* {
        void* p = (void*)wsp;
        wsp += ((bytes + 63) / 64) * 64;
        return p;
    };
    size_t bufBytes = ((((size_t)N * DIM * 2) + 63) / 64) * 64;

    int* degs   = (int*)alloc((size_t)2 * N * 4);
    int* deg_r  = degs;
    int* deg_c  = degs + N;
    int* rptr   = (int*)alloc(((size_t)N + 1) * 4);
    int* cptr   = (int*)alloc(((size_t)N + 1) * 4);
    int2* adj   = (int2*)alloc((size_t)E * 8);
    int2* adjT  = (int2*)alloc((size_t)E * 8);
    unsigned short* xb = (unsigned short*)alloc((size_t)N * DIM * 2);
    float* invs = (float*)alloc((size_t)2 * N * 4);
    float* inv_r = invs;
    float* inv_c = invs + N;
    float* cb   = (float*)alloc(64 * 4);
    unsigned short* Wall = (unsigned short*)alloc((size_t)9 * 4096 * 2);
    int* part   = (int*)alloc((size_t)2 * G * 4);
    int2* slot  = (int2*)alloc((size_t)E * 8);  // packed (slot_r, slot_c)

    size_t fixed_used = (size_t)(wsp - (char*)d_ws);
    bool mega = (fixed_used + 4 * bufBytes) <= ws_size;  // deterministic per session

    unsigned short* bufA = (unsigned short*)alloc((size_t)N * DIM * 2);
    unsigned short* bufB = (unsigned short*)alloc((size_t)N * DIM * 2);
    unsigned short* bufC = mega ? (unsigned short*)alloc((size_t)N * DIM * 2) : nullptr;
    unsigned short* bufD = mega ? (unsigned short*)alloc((size_t)N * DIM * 2) : nullptr;

    hipMemsetAsync(degs, 0, (size_t)2 * N * sizeof(int), stream);

    k_degrees<<<idiv(E, 256), 256, 0, stream>>>(row, col, deg_r, deg_c, slot, E);
    k_scan_blk<<<2 * G, 256, 0, stream>>>(deg_r, deg_c, part, N, G);
    k_scan_top<<<3, 1024, 0, stream>>>(part, G, bs_sd, b0_sd, bs_ds, b0_ds, cb);
    k_scan_fin<<<2 * G, 256, 0, stream>>>(deg_r, deg_c, part, rptr, cptr, inv_r, inv_c, N, G);
    k_fill<<<idiv(E, 256), 256, 0, stream>>>(row, col, rptr, cptr, slot,
                                             inv_r, inv_c, adj, adjT, E);
    k_xcast<<<idiv(N * DIM / 4, 256), 256, 0, stream>>>(x, xb, N * DIM);
    k_wprep<<<144, 256, 0, stream>>>(Ws_sd, Ws_ds, W0_sd, W0_ds, Wall);

    int spmmGrid = idiv(N * 64, 256);  // one wave per row
    int mgGrid = 512;                  // 2048 waves, ~3 tiles/wave amortize weight load

    if (mega) {
        // y0=A x->A ; yt0=A^T x->B ; y1=A y0->C ; yt1=A^T y1->D
        k_spmm<<<spmmGrid, 256, 0, stream>>>(xb, bufA, rptr, adj, inv_r, N);
        k_spmm<<<spmmGrid, 256, 0, stream>>>(xb, bufB, cptr, adjT, inv_c, N);
        k_spmm<<<spmmGrid, 256, 0, stream>>>(bufA, bufC, rptr, adj, inv_r, N);
        k_spmm<<<spmmGrid, 256, 0, stream>>>(bufC, bufD, cptr, adjT, inv_c, N);
        // out = cb + W0c x + Wsd0 y0 + Wds0 yt0 + Wsd1 y1 + Wds1 yt1   (mats 0..4)
        k_mg<5, true><<<mgGrid, 256, 0, stream>>>(xb, bufA, bufB, bufC, bufD, Wall, cb, out, N);
        // y2=A y1->A ; yt2=A^T y2->B ; y3=A y2->C ; yt3=A^T y3->D
        k_spmm<<<spmmGrid, 256, 0, stream>>>(bufC, bufA, rptr, adj, inv_r, N);
        k_spmm<<<spmmGrid, 256, 0, stream>>>(bufA, bufB, cptr, adjT, inv_c, N);
        k_spmm<<<spmmGrid, 256, 0, stream>>>(bufA, bufC, rptr, adj, inv_r, N);
        k_spmm<<<spmmGrid, 256, 0, stream>>>(bufC, bufD, cptr, adjT, inv_c, N);
        // out += Wsd2 y2 + Wds2 yt2 + Wsd3 y3 + Wds3 yt3   (mats 5..8)
        k_mg<4, false><<<mgGrid, 256, 0, stream>>>(bufA, bufB, bufC, bufD, nullptr,
                                                   Wall + (size_t)5 * 4096, cb, out, N);
    } else {
        // fallback: round-5 structure with 2 rotating buffers
        k_spmm<<<spmmGrid, 256, 0, stream>>>(xb, bufA, rptr, adj, inv_r, N);
        k_spmm<<<spmmGrid, 256, 0, stream>>>(xb, bufB, cptr, adjT, inv_c, N);
        k_mg<3, true><<<mgGrid, 256, 0, stream>>>(xb, bufA, bufB, nullptr, nullptr, Wall, cb, out, N);
        unsigned short* ycur = bufA;
        unsigned short* yfree = bufB;
        for (int i = 1; i < 4; i++) {
            k_spmm<<<spmmGrid, 256, 0, stream>>>(ycur, yfree, rptr, adj, inv_r, N);
            k_spmm<<<spmmGrid, 256, 0, stream>>>(yfree, ycur, cptr, adjT, inv_c, N);
            k_mg<2, false><<<mgGrid, 256, 0, stream>>>(yfree, ycur, nullptr, nullptr, nullptr,
                                                       Wall + (size_t)(2 * i + 1) * 4096, cb, out, N);
            unsigned short* t = ycur; ycur = yfree; yfree = t;
        }
    }
}

// Round 9
// 686.297 us; speedup vs baseline: 1.6262x; 1.3073x over previous
//
#include <hip/hip_runtime.h>
#include <hip/hip_bf16.h>

#define DIM 64
#define SCAN_CHUNK 2048

typedef __bf16 bf16v8 __attribute__((ext_vector_type(8)));
typedef float f32v4 __attribute__((ext_vector_type(4)));

static inline int idiv(int a, int b) { return (a + b - 1) / b; }

__device__ inline unsigned short f2b(float f) {
    __hip_bfloat16 h = __float2bfloat16(f);
    return *reinterpret_cast<unsigned short*>(&h);
}
__device__ inline float b2f(unsigned short u) {
    __hip_bfloat16 h;
    *reinterpret_cast<unsigned short*>(&h) = u;
    return __bfloat162float(h);
}

// ---------------- degrees + slot reservation (packed int2 slot store) ----------
__global__ void k_degrees(const int* __restrict__ row, const int* __restrict__ col,
                          int* __restrict__ dr, int* __restrict__ dc,
                          int2* __restrict__ slot, int E) {
    int e = blockIdx.x * blockDim.x + threadIdx.x;
    if (e < E) {
        int sr = atomicAdd(&dr[row[e]], 1);
        int sc = atomicAdd(&dc[col[e]], 1);
        slot[e] = make_int2(sr, sc);
    }
}

// ---------------- scan phase A: per-block partial sums ----------------
__global__ __launch_bounds__(256) void k_scan_blk(const int* __restrict__ deg_r,
                                                  const int* __restrict__ deg_c,
                                                  int* __restrict__ part, int n, int G) {
    int b = blockIdx.x;
    const int* deg = (b < G) ? deg_r : deg_c;
    int lb = (b < G) ? b : b - G;
    int base = lb * SCAN_CHUNK;
    int t = threadIdx.x;
    int s = 0;
    for (int i = t; i < SCAN_CHUNK; i += 256) {
        int g = base + i;
        if (g < n) s += deg[g];
    }
    __shared__ int red[256];
    red[t] = s;
    __syncthreads();
    for (int off = 128; off > 0; off >>= 1) {
        if (t < off) red[t] += red[t + off];
        __syncthreads();
    }
    if (t == 0) part[b] = red[0];
}

// ---------------- scan phase B: top scan (+ bias prep in spare block) ----------
__global__ __launch_bounds__(1024) void k_scan_top(int* __restrict__ part, int G,
        const float* __restrict__ bs_sd, const float* __restrict__ b0_sd,
        const float* __restrict__ bs_ds, const float* __restrict__ b0_ds,
        float* __restrict__ cb) {
    int t = threadIdx.x;
    if (blockIdx.x == 2) {
        if (t < 64) {
            float ssd = bs_sd[t] + b0_sd[t];
            float sds = bs_ds[t] + b0_ds[t];
            float sc = 1.f;
            for (int i = 1; i < 4; i++) {
                sc *= 0.5f;
                ssd += bs_sd[i * 64 + t] * sc;
                sds += bs_ds[i * 64 + t] * sc;
            }
            cb[t] = 0.5f * ssd + 0.5f * sds;  // ALPHA = 0.5
        }
        return;
    }
    int* p = part + ((blockIdx.x == 0) ? 0 : G);
    __shared__ int sums[1024];
    sums[t] = (t < G) ? p[t] : 0;
    __syncthreads();
    for (int off = 1; off < 1024; off <<= 1) {
        int v = (t >= off) ? sums[t - off] : 0;
        __syncthreads();
        sums[t] += v;
        __syncthreads();
    }
    if (t < G) p[t] = (t == 0) ? 0 : sums[t - 1];
}

// ---------------- scan phase C: finish — write ptr + inv ----------------
__global__ __launch_bounds__(256) void k_scan_fin(const int* __restrict__ deg_r,
                                                  const int* __restrict__ deg_c,
                                                  const int* __restrict__ part,
                                                  int* __restrict__ rptr, int* __restrict__ cptr,
                                                  float* __restrict__ inv_r, float* __restrict__ inv_c,
                                                  int n, int G) {
    int b = blockIdx.x;
    bool isr = (b < G);
    const int* deg = isr ? deg_r : deg_c;
    int* ptr = isr ? rptr : cptr;
    float* inv = isr ? inv_r : inv_c;
    int lb = isr ? b : b - G;
    int off = part[b];
    int base = lb * SCAN_CHUNK;
    int t = threadIdx.x;
    int start = base + t * 8;
    int v[8];
    int s = 0;
#pragma unroll
    for (int k = 0; k < 8; k++) {
        int g = start + k;
        int d = (g < n) ? deg[g] : 0;
        v[k] = d;
        s += d;
    }
    __shared__ int sums[256];
    sums[t] = s;
    __syncthreads();
    for (int o = 1; o < 256; o <<= 1) {
        int x = (t >= o) ? sums[t - o] : 0;
        __syncthreads();
        sums[t] += x;
        __syncthreads();
    }
    int run = off + ((t == 0) ? 0 : sums[t - 1]);
#pragma unroll
    for (int k = 0; k < 8; k++) {
        int g = start + k;
        if (g < n) {
            ptr[g] = run;
            inv[g] = (v[k] > 0) ? rsqrtf((float)v[k]) : 0.f;
            run += v[k];
        }
    }
    if (t == 255 && lb == G - 1) ptr[n] = run;  // grand total
}

// ---------------- CSR/CSC fill (atomic-free, packed idx+weight) ----------------
__global__ void k_fill(const int* __restrict__ row, const int* __restrict__ col,
                       const int* __restrict__ rptr, const int* __restrict__ cptr,
                       const int2* __restrict__ slot,
                       const float* __restrict__ inv_r, const float* __restrict__ inv_c,
                       int2* __restrict__ adj, int2* __restrict__ adjT, int E) {
    int e = blockIdx.x * blockDim.x + threadIdx.x;
    if (e < E) {
        int r = row[e], c = col[e];
        int2 s = slot[e];
        adj[rptr[r] + s.x] = make_int2(c, __float_as_int(inv_c[c]));
        adjT[cptr[c] + s.y] = make_int2(r, __float_as_int(inv_r[r]));
    }
}

// ---------------- x -> bf16 cast ----------------
__global__ void k_xcast(const float* __restrict__ x, unsigned short* __restrict__ xb, int total) {
    int i = (blockIdx.x * blockDim.x + threadIdx.x) * 4;
    if (i < total) {
        float4 v = *reinterpret_cast<const float4*>(x + i);
        ushort4 o;
        o.x = f2b(v.x); o.y = f2b(v.y); o.z = f2b(v.z); o.w = f2b(v.w);
        *reinterpret_cast<ushort4*>(xb + i) = o;
    }
}

// ---------------- weight prep: bf16 cast, scale prefolded ----------------
// Layout: m=0: W0c = 0.5*(W0_sd+W0_ds); m=1..4: 0.5*2^-(m-1)*Ws_sd[m-1];
//         m=5..8: 0.5*2^-(m-5)*Ws_ds[m-5]
__global__ void k_wprep(const float* __restrict__ Ws_sd, const float* __restrict__ Ws_ds,
                        const float* __restrict__ W0_sd, const float* __restrict__ W0_ds,
                        unsigned short* __restrict__ Wall) {
    int i = blockIdx.x * blockDim.x + threadIdx.x;  // 9*4096 total
    if (i >= 9 * 4096) return;
    int m = i >> 12, src = i & 4095;
    float v;
    if (m == 0) {
        v = 0.5f * (W0_sd[src] + W0_ds[src]);
    } else if (m < 5) {
        int hop = m - 1;
        v = Ws_sd[hop * 4096 + src] * (0.5f / (float)(1 << hop));
    } else {
        int hop = m - 5;
        v = Ws_ds[hop * 4096 + src] * (0.5f / (float)(1 << hop));
    }
    Wall[i] = f2b(v);
}

// ---------------- SpMM (bf16 h, bf16 out, fp32 accum) — proven body ------------
__global__ __launch_bounds__(256) void k_spmm(const unsigned short* __restrict__ h,
                                              unsigned short* __restrict__ out,
                                              const int* __restrict__ ptr,
                                              const int2* __restrict__ adj,
                                              const float* __restrict__ inv_self, int n) {
    int gw = (blockIdx.x * blockDim.x + threadIdx.x) >> 6;
    int lane = threadIdx.x & 63;
    if (gw >= n) return;
    int beg = ptr[gw], end = ptr[gw + 1];
    float acc = 0.f;
#pragma unroll 8
    for (int j = beg; j < end; j++) {
        int2 e = adj[j];
        acc = fmaf(__int_as_float(e.y), b2f(h[e.x * DIM + lane]), acc);
    }
    out[gw * DIM + lane] = f2b(inv_self[gw] * acc);
}

// ---------------- SpMM-accumulate into fp32 out (final A^T z pass) --------------
__global__ __launch_bounds__(256) void k_spmm_acc(const unsigned short* __restrict__ h,
                                                  float* __restrict__ out,
                                                  const int* __restrict__ ptr,
                                                  const int2* __restrict__ adj,
                                                  const float* __restrict__ inv_self, int n) {
    int gw = (blockIdx.x * blockDim.x + threadIdx.x) >> 6;
    int lane = threadIdx.x & 63;
    if (gw >= n) return;
    int beg = ptr[gw], end = ptr[gw + 1];
    float acc = 0.f;
#pragma unroll 8
    for (int j = beg; j < end; j++) {
        int2 e = adj[j];
        acc = fmaf(__int_as_float(e.y), b2f(h[e.x * DIM + lane]), acc);
    }
    out[gw * DIM + lane] += inv_self[gw] * acc;
}

// ---------------- multi-matrix MFMA GEMM, VGPR-resident weights ----------------
// out (=|+=) [bias +] sum_m W_m h_m ; scales prefolded into W. Per-matrix W ptrs.
// BF16OUT: write bf16 (z pass, INIT, no bias, no RMW).
template <int NM, bool INIT, bool BF16OUT>
__global__ __launch_bounds__(256, 2) void k_mg(
        const unsigned short* __restrict__ h0, const unsigned short* __restrict__ h1,
        const unsigned short* __restrict__ h2, const unsigned short* __restrict__ h3,
        const unsigned short* __restrict__ h4,
        const unsigned short* __restrict__ W0, const unsigned short* __restrict__ W1,
        const unsigned short* __restrict__ W2, const unsigned short* __restrict__ W3,
        const unsigned short* __restrict__ W4,
        const float* __restrict__ cb, void* __restrict__ outv, int n) {
    const unsigned short* hs[5] = {h0, h1, h2, h3, h4};
    const unsigned short* Ws[5] = {W0, W1, W2, W3, W4};
    float* outf = (float*)outv;
    unsigned short* outb = (unsigned short*)outv;
    int lane = threadIdx.x & 63;
    int quad = lane >> 4;
    int l16 = lane & 15;
    int nmax = n - 1;

    bf16v8 w[NM][4][2];
#pragma unroll
    for (int m = 0; m < NM; m++)
#pragma unroll
        for (int ot = 0; ot < 4; ot++)
#pragma unroll
            for (int kh = 0; kh < 2; kh++)
                w[m][ot][kh] = *reinterpret_cast<const bf16v8*>(
                    Ws[m] + (size_t)(ot * 16 + l16) * 64 + kh * 32 + quad * 8);

    float bias[4];
    if (INIT) {
#pragma unroll
        for (int ot = 0; ot < 4; ot++) bias[ot] = cb ? cb[ot * 16 + l16] : 0.f;
    }
    int tiles_all = (n + 15) >> 4;
    int wave = (blockIdx.x * blockDim.x + threadIdx.x) >> 6;
    int nw = (gridDim.x * blockDim.x) >> 6;
    for (int t = wave; t < tiles_all; t += nw) {
        int row0 = t << 4;
        int arow = min(row0 + l16, nmax);
        bf16v8 a[NM][2];
#pragma unroll
        for (int m = 0; m < NM; m++) {
            const bf16v8* p = reinterpret_cast<const bf16v8*>(hs[m] + (size_t)arow * 64 + quad * 8);
            a[m][0] = p[0];
            a[m][1] = p[4];
        }
        f32v4 acc[4];
        if (INIT) {
#pragma unroll
            for (int ot = 0; ot < 4; ot++) {
                float b = bias[ot];
                acc[ot] = f32v4{b, b, b, b};
            }
        } else {
#pragma unroll
            for (int ot = 0; ot < 4; ot++)
#pragma unroll
                for (int r = 0; r < 4; r++)
                    acc[ot][r] = outf[(size_t)min(row0 + quad * 4 + r, nmax) * 64 + ot * 16 + l16];
        }
#pragma unroll
        for (int ot = 0; ot < 4; ot++)
#pragma unroll
            for (int m = 0; m < NM; m++) {
                acc[ot] = __builtin_amdgcn_mfma_f32_16x16x32_bf16(a[m][0], w[m][ot][0], acc[ot], 0, 0, 0);
                acc[ot] = __builtin_amdgcn_mfma_f32_16x16x32_bf16(a[m][1], w[m][ot][1], acc[ot], 0, 0, 0);
            }
#pragma unroll
        for (int ot = 0; ot < 4; ot++)
#pragma unroll
            for (int r = 0; r < 4; r++) {
                int rr = row0 + quad * 4 + r;
                if (rr < n) {
                    if (BF16OUT) outb[(size_t)rr * 64 + ot * 16 + l16] = f2b(acc[ot][r]);
                    else         outf[(size_t)rr * 64 + ot * 16 + l16] = acc[ot][r];
                }
            }
    }
}

extern "C" void kernel_launch(void* const* d_in, const int* in_sizes, int n_in,
                              void* d_out, int out_size, void* d_ws, size_t ws_size,
                              hipStream_t stream) {
    const float* x     = (const float*)d_in[0];
    const int*   ei    = (const int*)d_in[1];
    const float* Ws_sd = (const float*)d_in[2];
    const float* bs_sd = (const float*)d_in[3];
    const float* Ws_ds = (const float*)d_in[4];
    const float* bs_ds = (const float*)d_in[5];
    const float* W0_sd = (const float*)d_in[6];
    const float* b0_sd = (const float*)d_in[7];
    const float* W0_ds = (const float*)d_in[8];
    const float* b0_ds = (const float*)d_in[9];

    int N = in_sizes[0] / DIM;
    int E = in_sizes[1] / 2;
    const int* row = ei;
    const int* col = ei + E;
    float* out = (float*)d_out;

    int G = idiv(N, SCAN_CHUNK);

    char* wsp = (char*)d_ws;
    auto alloc = [&](size_t bytes) -> void* {
        void* p = (void*)wsp;
        wsp += ((bytes + 63) / 64) * 64;
        return p;
    };
    size_t bufBytes = ((((size_t)N * DIM * 2) + 63) / 64) * 64;

    int* degs   = (int*)alloc((size_t)2 * N * 4);
    int* deg_r  = degs;
    int* deg_c  = degs + N;
    int* rptr   = (int*)alloc(((size_t)N + 1) * 4);
    int* cptr   = (int*)alloc(((size_t)N + 1) * 4);
    int2* adj   = (int2*)alloc((size_t)E * 8);
    int2* adjT  = (int2*)alloc((size_t)E * 8);
    unsigned short* xb = (unsigned short*)alloc((size_t)N * DIM * 2);
    float* invs = (float*)alloc((size_t)2 * N * 4);
    float* inv_r = invs;
    float* inv_c = invs + N;
    float* cb   = (float*)alloc(64 * 4);
    unsigned short* Wall = (unsigned short*)alloc((size_t)9 * 4096 * 2);
    int* part   = (int*)alloc((size_t)2 * G * 4);
    int2* slot  = (int2*)alloc((size_t)E * 8);  // packed (slot_r, slot_c); dead after k_fill

    size_t fixed_used = (size_t)(wsp - (char*)d_ws);
    bool mega = (fixed_used + 4 * bufBytes) <= ws_size;

    unsigned short* bufA = (unsigned short*)alloc((size_t)N * DIM * 2);
    unsigned short* bufB = (unsigned short*)alloc((size_t)N * DIM * 2);
    unsigned short* bufC = mega ? (unsigned short*)alloc((size_t)N * DIM * 2) : nullptr;
    unsigned short* bufD = mega ? (unsigned short*)alloc((size_t)N * DIM * 2) : nullptr;

    // z aliases slot: E*8 bytes = 12.8 MB >= N*64*2 = 12.8 MB; slot dead after k_fill
    unsigned short* zb = (unsigned short*)slot;

    hipMemsetAsync(degs, 0, (size_t)2 * N * sizeof(int), stream);

    k_degrees<<<idiv(E, 256), 256, 0, stream>>>(row, col, deg_r, deg_c, slot, E);
    k_scan_blk<<<2 * G, 256, 0, stream>>>(deg_r, deg_c, part, N, G);
    k_scan_top<<<3, 1024, 0, stream>>>(part, G, bs_sd, b0_sd, bs_ds, b0_ds, cb);
    k_scan_fin<<<2 * G, 256, 0, stream>>>(deg_r, deg_c, part, rptr, cptr, inv_r, inv_c, N, G);
    k_fill<<<idiv(E, 256), 256, 0, stream>>>(row, col, rptr, cptr, slot,
                                             inv_r, inv_c, adj, adjT, E);
    k_xcast<<<idiv(N * DIM / 4, 256), 256, 0, stream>>>(x, xb, N * DIM);
    k_wprep<<<144, 256, 0, stream>>>(Ws_sd, Ws_ds, W0_sd, W0_ds, Wall);

    const unsigned short* W0c = Wall;
    const unsigned short* Wsd[4] = {Wall + 4096, Wall + 2 * 4096, Wall + 3 * 4096, Wall + 4 * 4096};
    const unsigned short* Wds[4] = {Wall + 5 * 4096, Wall + 6 * 4096, Wall + 7 * 4096, Wall + 8 * 4096};

    int spmmGrid = idiv(N * 64, 256);
    int mgGrid = 512;

    if (mega) {
        // A-chain: y0..y3
        k_spmm<<<spmmGrid, 256, 0, stream>>>(xb, bufA, rptr, adj, inv_r, N);    // y0
        k_spmm<<<spmmGrid, 256, 0, stream>>>(bufA, bufB, rptr, adj, inv_r, N);  // y1
        k_spmm<<<spmmGrid, 256, 0, stream>>>(bufB, bufC, rptr, adj, inv_r, N);  // y2
        k_spmm<<<spmmGrid, 256, 0, stream>>>(bufC, bufD, rptr, adj, inv_r, N);  // y3
        // z = s0 x Wds0^T + s1 y1 Wds1^T + s2 y2 Wds2^T + s3 y3 Wds3^T  (bf16)
        k_mg<4, true, true><<<mgGrid, 256, 0, stream>>>(
            xb, bufB, bufC, bufD, nullptr,
            Wds[0], Wds[1], Wds[2], Wds[3], nullptr, nullptr, zb, N);
        // out = cb + W0c x + s0 y0 Wsd0^T + ... + s3 y3 Wsd3^T  (fp32)
        k_mg<5, true, false><<<mgGrid, 256, 0, stream>>>(
            xb, bufA, bufB, bufC, bufD,
            W0c, Wsd[0], Wsd[1], Wsd[2], Wsd[3], cb, out, N);
        // out += A^T z
        k_spmm_acc<<<spmmGrid, 256, 0, stream>>>(zb, out, cptr, adjT, inv_c, N);
    } else {
        // fallback: round-5 structure with 2 rotating buffers (8 SpMMs)
        k_spmm<<<spmmGrid, 256, 0, stream>>>(xb, bufA, rptr, adj, inv_r, N);
        k_spmm<<<spmmGrid, 256, 0, stream>>>(xb, bufB, cptr, adjT, inv_c, N);
        k_mg<3, true, false><<<mgGrid, 256, 0, stream>>>(
            xb, bufA, bufB, nullptr, nullptr,
            W0c, Wsd[0], Wds[0], nullptr, nullptr, cb, out, N);
        unsigned short* ycur = bufA;
        unsigned short* yfree = bufB;
        for (int i = 1; i < 4; i++) {
            k_spmm<<<spmmGrid, 256, 0, stream>>>(ycur, yfree, rptr, adj, inv_r, N);
            k_spmm<<<spmmGrid, 256, 0, stream>>>(yfree, ycur, cptr, adjT, inv_c, N);
            k_mg<2, false, false><<<mgGrid, 256, 0, stream>>>(
                yfree, ycur, nullptr, nullptr, nullptr,
                Wsd[i], Wds[i], nullptr, nullptr, nullptr, nullptr, out, N);
            unsigned short* t = ycur; ycur = yfree; yfree = t;
        }
    }
}